// Round 3
// baseline (27028.961 us; speedup 1.0000x reference)
//
#include <hip/hip_runtime.h>
#include <hip/hip_fp16.h>
#include <stdint.h>

// LSTM_29042568856007: B=64, T=4096, D=256, H=256.
// Round 7: de-serialize the timestep. R5->R6 refuted stream-BW-bound (moving
// 16KB/step stream->LDS changed nothing). Accounting shows VALU ~24%, LDS ~15%,
// L2 ~29% of the 9.3k-cyc step -- they fail to overlap because TWO
// __syncthreads per step (each = s_waitcnt vmcnt(0) lgkmcnt(0) + s_barrier)
// lockstep all 16 waves, and the elementwise phase ran in only 4 waves.
// Changes:
//  (1) gate-row permutation: row q*256+j -> thread 4j+q. All 4 gates of h-row j
//      are in adjacent lanes of ONE wave: i/f/g/o gathered by 3 shfl_xor,
//      g_s + bar-G deleted, elementwise runs in all 16 waves (4x redundant).
//  (2) raw barrier (s_waitcnt lgkmcnt(0); s_barrier): global loads stay in
//      flight across the barrier (no vmcnt(0) drain).
//  (3) stream weights prefetched for step t+1 right after step t consumes them
//      (h-independent) -> a full step of latency cover.
// Barriers/step: 2 -> 1. W_hh residency unchanged: k4 0..15 reg(+pin),
// 16..24 LDS (144 KiB), 25..31 re-issued from L2 (112 KB/step).

#define LSTM_B 64
#define LSTM_T 4096
#define LSTM_D 256
#define LSTM_H 256
#define NX 8
#define NG (LSTM_T / NX)
#define NREG 16
#define NLDS 9
#define NSTR 7

typedef __attribute__((ext_vector_type(2))) _Float16 half2_t;

static __device__ __forceinline__ float dot2(uint32_t w, uint32_t a, float acc) {
#if __has_builtin(__builtin_amdgcn_fdot2)
    return __builtin_amdgcn_fdot2(__builtin_bit_cast(half2_t, w),
                                  __builtin_bit_cast(half2_t, a), acc, false);
#else
    __half2 hw = __builtin_bit_cast(__half2, w);
    __half2 ha = __builtin_bit_cast(__half2, a);
    acc = fmaf(__low2float(hw), __low2float(ha), acc);
    acc = fmaf(__high2float(hw), __high2float(ha), acc);
    return acc;
#endif
}

// LDS-ordering barrier that does NOT drain vmcnt: streamed/prefetched global
// loads stay in flight across it. lgkmcnt(0) orders the h_u/x_u ds ops.
#define BAR() asm volatile("s_waitcnt lgkmcnt(0)\n\ts_barrier" ::: "memory")

// ws: uint4 Wp[64][1024] (k4, slot), 1 MiB packed f16 pairs.
//   k4 in [0,32): W_ih; k4 in [32,64): W_hh.
// Row permutation: slot s holds source row r = (s&3)*256 + (s>>2), so thread
// tid=4j+q owns gate-q row of h-row j for both weight matrices.
__global__ __launch_bounds__(256) void prep_weights(
    const float* __restrict__ W_ih, const float* __restrict__ W_hh,
    uint32_t* __restrict__ Wp)
{
    int idx = blockIdx.x * blockDim.x + threadIdx.x;  // [0, 262144)
    if (idx >= 64 * 1024 * 4) return;
    int e  = idx & 3;
    int s  = (idx >> 2) & 1023;                 // packed slot
    int k4 = idx >> 12;
    int k  = ((k4 & 31) << 3) + (e << 1);
    int r  = ((s & 3) << 8) + (s >> 2);         // source row (gate, h-row)
    const float* W = (k4 < 32) ? W_ih : W_hh;
    uint32_t lo = (uint32_t)__half_as_ushort(__float2half(W[r * 256 + k]));
    uint32_t hi = (uint32_t)__half_as_ushort(__float2half(W[r * 256 + k + 1]));
    Wp[idx] = lo | (hi << 16);
}

static __device__ __forceinline__ float sigmoidf_(float x) {
    return 1.0f / (1.0f + __expf(-x));
}
static __device__ __forceinline__ float tanhf_(float x) {
    float ax = fabsf(x);
    float e  = __expf(-2.0f * ax);
    float t  = (1.0f - e) / (1.0f + e);
    return copysignf(t, x);
}

#define DOT4(wv, hv) do { \
    acc0 = dot2((wv).x, (hv).x, acc0); \
    acc1 = dot2((wv).y, (hv).y, acc1); \
    acc0 = dot2((wv).z, (hv).z, acc0); \
    acc1 = dot2((wv).w, (hv).w, acc1); } while (0)

__global__ __attribute__((amdgpu_flat_work_group_size(1024, 1024),
                          amdgpu_waves_per_eu(4, 4)))
void lstm_r7(
    const float* __restrict__ xs,     // [B, T, D] fp32
    const float* __restrict__ bias_g, // [4H]
    const uint4* __restrict__ Wp,     // [64][1024] f16-pair octets (permuted rows)
    float* __restrict__ out)          // h[B,H] then c[B,H]
{
    __shared__ __align__(16) uint4    wlds[NLDS * 1024]; // 144 KiB: W_hh k4=16..24
    __shared__ __align__(16) uint32_t x_u[NX * 128];     // 4 KiB (f16-packed x)
    __shared__ __align__(16) uint32_t h_u[128];          // 512 B (f16-packed h)

    const int tid = threadIdx.x;   // owns gate row (tid&3)*256 + (tid>>2)
    const int b   = blockIdx.x;    // batch element
    const int j   = tid >> 2;      // h-row
    const bool q0 = (tid & 1) != 0;
    const bool q1 = (tid & 2) != 0;

    const float bias = bias_g[((tid & 3) << 8) + j];
    const float* xrow = xs + (size_t)b * LSTM_T * LSTM_D;

    const uint4* Wih = Wp + tid;                              // k4 in [0,32)
    const uint4* Whr = Wp + (32 << 10) + tid;                 // W_hh reg    k4 0..15
    const uint4* Whl = Wp + ((32 + NREG) << 10) + tid;        // W_hh LDS    k4 16..24
    const uint4* Whs = Wp + ((32 + NREG + NLDS) << 10) + tid; // W_hh stream k4 25..31
    const uint4* x_u4 = (const uint4*)x_u;
    const uint4* h_u4 = (const uint4*)h_u;

    // ---- one-time: W_hh k4=0..15 into registers/AGPRs (64 regs) ----
    uint4 wreg[NREG];
    #pragma unroll
    for (int i = 0; i < NREG; ++i) wreg[i] = Whr[i << 10];
    #pragma unroll
    for (int i = 0; i < NREG; ++i) {
        asm volatile("" : "+v"(wreg[i].x), "+v"(wreg[i].y),
                          "+v"(wreg[i].z), "+v"(wreg[i].w));
    }

    // ---- one-time: W_hh k4=16..24 into LDS (144 KiB) ----
    #pragma unroll
    for (int i = 0; i < NLDS; ++i)
        wlds[(i << 10) + tid] = Whl[i << 10];

    if (tid < 128) h_u[tid] = 0u;
    float c = 0.0f, hlast = 0.0f;

    // prefetch group 0's x
    float2 xpre = ((const float2*)xrow)[tid];

    // prologue stream-weight fetch (re-issued each step; h-independent)
    uint4 wss[NSTR];
    #pragma unroll
    for (int i = 0; i < NSTR; ++i) wss[i] = Whs[i << 10];

    for (int tg = 0; tg < NG; ++tg) {
        // ---- stage packed-f16 x for this group; prefetch next group ----
        {
            __half2 p = __floats2half2_rn(xpre.x, xpre.y);
            x_u[tid] = __builtin_bit_cast(uint32_t, p);  // tid = tt*128 + kpair
            int ng = (tg + 1 < NG) ? tg + 1 : tg;
            xpre = ((const float2*)(xrow + (size_t)ng * NX * LSTM_D))[tid];
        }
        BAR();             // x_u ready (covers wlds/h_u init on tg=0)

        // ---- x-pass: xacc[tt] = bias + W_ih[row,:].x_t (registers) ----
        float xacc[NX];
        #pragma unroll
        for (int tt = 0; tt < NX; ++tt) xacc[tt] = bias;
        #pragma unroll 2
        for (int k4 = 0; k4 < 32; ++k4) {
            uint4 w = Wih[k4 << 10];
            #pragma unroll
            for (int tt = 0; tt < NX; ++tt) {
                uint4 xa = x_u4[tt * 32 + k4];   // wave-uniform -> broadcast
                float s = xacc[tt];
                s = dot2(w.x, xa.x, s);
                s = dot2(w.y, xa.y, s);
                s = dot2(w.z, xa.z, s);
                s = dot2(w.w, xa.w, s);
                xacc[tt] = s;
            }
        }

        // ---- NX recurrence steps: ONE barrier each ----
        #pragma unroll 1
        for (int tt = 0; tt < NX; ++tt) {
            float acc0 = xacc[tt];
            float acc1 = 0.0f;

            // register-resident W_hh: k4 = 0..15
            #pragma unroll
            for (int k4 = 0; k4 < NREG; ++k4) {
                uint4 ha = h_u4[k4];             // wave-uniform -> broadcast
                DOT4(wreg[k4], ha);
            }
            // LDS-resident W_hh: k4 = 16..24
            #pragma unroll
            for (int i = 0; i < NLDS; ++i) {
                uint4 w  = wlds[(i << 10) + tid];
                uint4 ha = h_u4[NREG + i];
                DOT4(w, ha);
            }
            // streamed W_hh: k4 = 25..31 (prefetched last step)
            #pragma unroll
            for (int i = 0; i < NSTR; ++i) {
                uint4 ha = h_u4[NREG + NLDS + i];
                DOT4(wss[i], ha);
            }
            // re-issue stream loads for next step: in flight across the
            // barrier (BAR does not drain vmcnt) -> full-step latency cover
            #pragma unroll
            for (int i = 0; i < NSTR; ++i) wss[i] = Whs[i << 10];

            // gather i,f,g,o within the lane quad (3 shfls, no LDS, no barrier)
            float own = acc0 + acc1;                 // gate (tid&3) of h-row j
            float va = __shfl_xor(own, 1, 64);       // gate q^1
            float vb = __shfl_xor(own, 2, 64);       // gate q^2
            float vd = __shfl_xor(va, 2, 64);        // gate q^3
            float gi = q1 ? (q0 ? vd : vb) : (q0 ? va : own);
            float gf = q1 ? (q0 ? vb : vd) : (q0 ? own : va);
            float gg = q1 ? (q0 ? va : own) : (q0 ? vd : vb);
            float go = q1 ? (q0 ? own : va) : (q0 ? vb : vd);

            // elementwise in ALL lanes (4x redundant per h-row, no idle waves)
            c = sigmoidf_(gf) * c + sigmoidf_(gi) * tanhf_(gg);
            hlast = sigmoidf_(go) * tanhf_(c);

            // pack h: even-j q0-lanes combine h_j with h_{j+1} (4 lanes away)
            uint32_t u  = (uint32_t)__half_as_ushort(__float2half(hlast));
            uint32_t up = (uint32_t)__shfl_xor((int)u, 4, 64);
            if ((tid & 7) == 0) h_u[tid >> 3] = (u & 0xffffu) | (up << 16);

            BAR();         // h_{t+1} visible; stream prefetch stays in flight
        }
    }

    if ((tid & 3) == 0) {
        out[b * LSTM_H + j]                   = hlast;  // h_T
        out[LSTM_B * LSTM_H + b * LSTM_H + j] = c;      // c_T
    }
}

extern "C" void kernel_launch(void* const* d_in, const int* in_sizes, int n_in,
                              void* d_out, int out_size, void* d_ws, size_t ws_size,
                              hipStream_t stream) {
    const float* xs   = (const float*)d_in[0];  // [64,4096,256]
    const float* W_ih = (const float*)d_in[1];  // [1024,256]
    const float* W_hh = (const float*)d_in[2];  // [1024,256]
    const float* b    = (const float*)d_in[3];  // [1024]
    float* out = (float*)d_out;
    uint32_t* Wp = (uint32_t*)d_ws;             // 1 MiB packed f16 weights

    prep_weights<<<1024, 256, 0, stream>>>(W_ih, W_hh, Wp);
    lstm_r7<<<LSTM_B, 1024, 0, stream>>>(xs, b, (const uint4*)Wp, out);
}

// Round 4
// 18070.845 us; speedup vs baseline: 1.4957x; 1.4957x over previous
//
#include <hip/hip_runtime.h>
#include <hip/hip_fp16.h>
#include <stdint.h>

// LSTM_29042568856007: B=64, T=4096, D=256, H=256.
// Round 8: halve the per-CU LDS-pipe traffic. R7 post-mortem: (a) regression
// was scratch spill (WRITE_SIZE 640KB->152MB) from holding 28 stream regs
// across the barrier -- unified reg budget at 16 waves/CU is ~128/lane;
// (b) the step-time model closes once LDS issue is counted: 16 waves *
// (8 x-bcast + 32 h-bcast + 9 wlds b128) ~= 5.8k cyc/step on the per-CU LDS
// pipe = the dominant cost. Fix: 512 threads, 2 gate-rows/thread:
//   - every x/h broadcast feeds 8 dot2 instead of 4 (LDS pipe halved)
//   - 8 waves/CU (2/SIMD) -> unified budget 256 regs: both rows' wreg (128)
//     fit spill-free with ~60 headroom
//   - keep R7's wins: permuted rows + quad-shuffle gates (no g_s, ONE
//     lgkm-only barrier/step); stream regs consumed within the step
//   - h_u double-buffered (R7's single-buffer write-before-barrier raced)
// Residency per row unchanged: k4 0..15 reg, 16..24 LDS, 25..31 stream.

#define LSTM_B 64
#define LSTM_T 4096
#define LSTM_D 256
#define LSTM_H 256
#define NX 8
#define NG (LSTM_T / NX)
#define NREG 16
#define NLDS 9
#define NSTR 7

typedef __attribute__((ext_vector_type(2))) _Float16 half2_t;

static __device__ __forceinline__ float dot2(uint32_t w, uint32_t a, float acc) {
#if __has_builtin(__builtin_amdgcn_fdot2)
    return __builtin_amdgcn_fdot2(__builtin_bit_cast(half2_t, w),
                                  __builtin_bit_cast(half2_t, a), acc, false);
#else
    __half2 hw = __builtin_bit_cast(__half2, w);
    __half2 ha = __builtin_bit_cast(__half2, a);
    acc = fmaf(__low2float(hw), __low2float(ha), acc);
    acc = fmaf(__high2float(hw), __high2float(ha), acc);
    return acc;
#endif
}

// LDS-ordering barrier that does NOT drain vmcnt.
#define BAR() asm volatile("s_waitcnt lgkmcnt(0)\n\ts_barrier" ::: "memory")

// ws: uint4 Wp[64][1024] (k4, slot), 1 MiB packed f16 pairs.
//   k4 in [0,32): W_ih; k4 in [32,64): W_hh.
// Row permutation: slot s holds source row r = (s&3)*256 + (s>>2).
__global__ __launch_bounds__(256) void prep_weights(
    const float* __restrict__ W_ih, const float* __restrict__ W_hh,
    uint32_t* __restrict__ Wp)
{
    int idx = blockIdx.x * blockDim.x + threadIdx.x;  // [0, 262144)
    if (idx >= 64 * 1024 * 4) return;
    int e  = idx & 3;
    int s  = (idx >> 2) & 1023;                 // packed slot
    int k4 = idx >> 12;
    int k  = ((k4 & 31) << 3) + (e << 1);
    int r  = ((s & 3) << 8) + (s >> 2);         // source row (gate, h-row)
    const float* W = (k4 < 32) ? W_ih : W_hh;
    uint32_t lo = (uint32_t)__half_as_ushort(__float2half(W[r * 256 + k]));
    uint32_t hi = (uint32_t)__half_as_ushort(__float2half(W[r * 256 + k + 1]));
    Wp[idx] = lo | (hi << 16);
}

static __device__ __forceinline__ float sigmoidf_(float x) {
    return 1.0f / (1.0f + __expf(-x));
}
static __device__ __forceinline__ float tanhf_(float x) {
    float ax = fabsf(x);
    float e  = __expf(-2.0f * ax);
    float t  = (1.0f - e) / (1.0f + e);
    return copysignf(t, x);
}

// one broadcast operand feeds both accumulator pairs of a row
#define DOT4P(wv, hv, p0, p1) do { \
    p0 = dot2((wv).x, (hv).x, p0); \
    p1 = dot2((wv).y, (hv).y, p1); \
    p0 = dot2((wv).z, (hv).z, p0); \
    p1 = dot2((wv).w, (hv).w, p1); } while (0)

__global__ __launch_bounds__(512, 2) void lstm_r8(
    const float* __restrict__ xs,     // [B, T, D] fp32
    const float* __restrict__ bias_g, // [4H]
    const uint4* __restrict__ Wp,     // [64][1024] f16-pair octets (permuted)
    float* __restrict__ out)          // h[B,H] then c[B,H]
{
    __shared__ __align__(16) uint4    wlds[NLDS * 1024]; // 144 KiB W_hh k4 16..24
    __shared__ __align__(16) uint32_t x_u[NX * 128];     // 4 KiB packed x
    __shared__ __align__(16) uint32_t h_u[2][128];       // 1 KiB packed h, dbuf

    const int t  = threadIdx.x;      // slots t (rowA) and t+512 (rowB)
    const int b  = blockIdx.x;
    const int jA = t >> 2;           // h-row of slot A (slot B: 128+jA)
    const bool q0 = (t & 1) != 0;
    const bool q1 = (t & 2) != 0;

    const float biasA = bias_g[((t & 3) << 8) + jA];
    const float biasB = bias_g[((t & 3) << 8) + 128 + jA];
    const float* xrow = xs + (size_t)b * LSTM_T * LSTM_D;

    const uint4* WihB = Wp;                              // + (k4<<10) + slot
    const uint4* WhrB = Wp + (32 << 10);                 // W_hh reg    k4 0..15
    const uint4* WhlB = Wp + ((32 + NREG) << 10);        // W_hh LDS    k4 16..24
    const uint4* WhsB = Wp + ((32 + NREG + NLDS) << 10); // W_hh stream k4 25..31
    const uint4* x_u4 = (const uint4*)x_u;

    // ---- one-time: W_hh k4=0..15 for both rows into regs (128 regs) ----
    uint4 wregA[NREG], wregB[NREG];
    #pragma unroll
    for (int i = 0; i < NREG; ++i) {
        wregA[i] = WhrB[(i << 10) + t];
        wregB[i] = WhrB[(i << 10) + t + 512];
    }
    #pragma unroll
    for (int i = 0; i < NREG; ++i) {
        asm volatile("" : "+v"(wregA[i].x), "+v"(wregA[i].y),
                          "+v"(wregA[i].z), "+v"(wregA[i].w));
        asm volatile("" : "+v"(wregB[i].x), "+v"(wregB[i].y),
                          "+v"(wregB[i].z), "+v"(wregB[i].w));
    }

    // ---- one-time: W_hh k4=16..24 into LDS ----
    #pragma unroll
    for (int i = 0; i < NLDS; ++i) {
        wlds[(i << 10) + t]       = WhlB[(i << 10) + t];
        wlds[(i << 10) + t + 512] = WhlB[(i << 10) + t + 512];
    }

    if (t < 128) h_u[0][t] = 0u;
    float cA = 0.0f, cB = 0.0f, hA = 0.0f, hB = 0.0f;
    int par = 0;

    // prefetch group 0's x (2 float2 per thread)
    float2 xpreA = ((const float2*)xrow)[t];
    float2 xpreB = ((const float2*)xrow)[t + 512];

    for (int tg = 0; tg < NG; ++tg) {
        // ---- stage packed-f16 x for this group; prefetch next group ----
        {
            __half2 pA = __floats2half2_rn(xpreA.x, xpreA.y);
            __half2 pB = __floats2half2_rn(xpreB.x, xpreB.y);
            x_u[t]       = __builtin_bit_cast(uint32_t, pA);
            x_u[t + 512] = __builtin_bit_cast(uint32_t, pB);
            int ng = (tg + 1 < NG) ? tg + 1 : tg;
            const float2* nx = (const float2*)(xrow + (size_t)ng * NX * LSTM_D);
            xpreA = nx[t];
            xpreB = nx[t + 512];
        }
        BAR();             // x_u ready (covers wlds/h_u init on tg=0)

        // ---- x-pass: both rows, shared x broadcasts (1 read : 8 dot2) ----
        float xaccA[NX], xaccB[NX];
        #pragma unroll
        for (int tt = 0; tt < NX; ++tt) { xaccA[tt] = biasA; xaccB[tt] = biasB; }
        #pragma unroll 2
        for (int k4 = 0; k4 < 32; ++k4) {
            uint4 wa = WihB[(k4 << 10) + t];
            uint4 wb = WihB[(k4 << 10) + t + 512];
            #pragma unroll
            for (int tt = 0; tt < NX; ++tt) {
                uint4 xa = x_u4[tt * 32 + k4];   // wave-uniform broadcast
                float a0 = xaccA[tt], b0 = xaccB[tt];
                a0 = dot2(wa.x, xa.x, a0); b0 = dot2(wb.x, xa.x, b0);
                a0 = dot2(wa.y, xa.y, a0); b0 = dot2(wb.y, xa.y, b0);
                a0 = dot2(wa.z, xa.z, a0); b0 = dot2(wb.z, xa.z, b0);
                a0 = dot2(wa.w, xa.w, a0); b0 = dot2(wb.w, xa.w, b0);
                xaccA[tt] = a0; xaccB[tt] = b0;
            }
        }

        // ---- NX recurrence steps: ONE barrier each ----
        #pragma unroll 1
        for (int tt = 0; tt < NX; ++tt) {
            const uint32_t* hbuf = h_u[par];
            const uint4* hp = (const uint4*)hbuf;
            uint32_t* hnext = h_u[par ^ 1];

            float a0 = xaccA[tt], a1 = 0.0f;
            float b0 = xaccB[tt], b1 = 0.0f;

            // stream chunk 1: k4 25..28, both rows (consumed this step only)
            uint4 wsA0 = WhsB[(0 << 10) + t], wsB0 = WhsB[(0 << 10) + t + 512];
            uint4 wsA1 = WhsB[(1 << 10) + t], wsB1 = WhsB[(1 << 10) + t + 512];
            uint4 wsA2 = WhsB[(2 << 10) + t], wsB2 = WhsB[(2 << 10) + t + 512];
            uint4 wsA3 = WhsB[(3 << 10) + t], wsB3 = WhsB[(3 << 10) + t + 512];

            // register-resident: k4 0..15 (1 h-broadcast : 8 dot2)
            #pragma unroll
            for (int k4 = 0; k4 < NREG; ++k4) {
                uint4 ha = hp[k4];
                DOT4P(wregA[k4], ha, a0, a1);
                DOT4P(wregB[k4], ha, b0, b1);
            }
            // LDS-resident: k4 16..24
            #pragma unroll
            for (int i = 0; i < NLDS; ++i) {
                uint4 wa = wlds[(i << 10) + t];
                uint4 wb = wlds[(i << 10) + t + 512];
                uint4 ha = hp[NREG + i];
                DOT4P(wa, ha, a0, a1);
                DOT4P(wb, ha, b0, b1);
            }
            // stream chunk 2: k4 29..31
            uint4 wsA4 = WhsB[(4 << 10) + t], wsB4 = WhsB[(4 << 10) + t + 512];
            uint4 wsA5 = WhsB[(5 << 10) + t], wsB5 = WhsB[(5 << 10) + t + 512];
            uint4 wsA6 = WhsB[(6 << 10) + t], wsB6 = WhsB[(6 << 10) + t + 512];

            { uint4 ha = hp[25]; DOT4P(wsA0, ha, a0, a1); DOT4P(wsB0, ha, b0, b1); }
            { uint4 ha = hp[26]; DOT4P(wsA1, ha, a0, a1); DOT4P(wsB1, ha, b0, b1); }
            { uint4 ha = hp[27]; DOT4P(wsA2, ha, a0, a1); DOT4P(wsB2, ha, b0, b1); }
            { uint4 ha = hp[28]; DOT4P(wsA3, ha, a0, a1); DOT4P(wsB3, ha, b0, b1); }
            { uint4 ha = hp[29]; DOT4P(wsA4, ha, a0, a1); DOT4P(wsB4, ha, b0, b1); }
            { uint4 ha = hp[30]; DOT4P(wsA5, ha, a0, a1); DOT4P(wsB5, ha, b0, b1); }
            { uint4 ha = hp[31]; DOT4P(wsA6, ha, a0, a1); DOT4P(wsB6, ha, b0, b1); }

            // gather i,f,g,o within the lane quad (verified in R7)
            float ownA = a0 + a1;
            float vaA = __shfl_xor(ownA, 1, 64);
            float vbA = __shfl_xor(ownA, 2, 64);
            float vdA = __shfl_xor(vaA, 2, 64);
            float giA = q1 ? (q0 ? vdA : vbA) : (q0 ? vaA : ownA);
            float gfA = q1 ? (q0 ? vbA : vdA) : (q0 ? ownA : vaA);
            float ggA = q1 ? (q0 ? vaA : ownA) : (q0 ? vdA : vbA);
            float goA = q1 ? (q0 ? ownA : vaA) : (q0 ? vbA : vdA);
            cA = sigmoidf_(gfA) * cA + sigmoidf_(giA) * tanhf_(ggA);
            hA = sigmoidf_(goA) * tanhf_(cA);

            float ownB = b0 + b1;
            float vaB = __shfl_xor(ownB, 1, 64);
            float vbB = __shfl_xor(ownB, 2, 64);
            float vdB = __shfl_xor(vaB, 2, 64);
            float giB = q1 ? (q0 ? vdB : vbB) : (q0 ? vaB : ownB);
            float gfB = q1 ? (q0 ? vbB : vdB) : (q0 ? ownB : vaB);
            float ggB = q1 ? (q0 ? vaB : ownB) : (q0 ? vdB : vbB);
            float goB = q1 ? (q0 ? ownB : vaB) : (q0 ? vbB : vdB);
            cB = sigmoidf_(gfB) * cB + sigmoidf_(giB) * tanhf_(ggB);
            hB = sigmoidf_(goB) * tanhf_(cB);

            // pack h into f16 pairs (partner = lane t^4, same gate, row j^1)
            uint32_t uA  = (uint32_t)__half_as_ushort(__float2half(hA));
            uint32_t upA = (uint32_t)__shfl_xor((int)uA, 4, 64);
            uint32_t uB  = (uint32_t)__half_as_ushort(__float2half(hB));
            uint32_t upB = (uint32_t)__shfl_xor((int)uB, 4, 64);
            if ((t & 7) == 0) {
                hnext[t >> 3]        = (uA & 0xffffu) | (upA << 16);  // rows 0..127
                hnext[64 + (t >> 3)] = (uB & 0xffffu) | (upB << 16);  // rows 128..255
            }

            BAR();         // h_{t+1} buffer visible
            par ^= 1;
        }
    }

    if ((t & 3) == 0) {
        out[b * LSTM_H + jA]                          = hA;
        out[b * LSTM_H + 128 + jA]                    = hB;
        out[LSTM_B * LSTM_H + b * LSTM_H + jA]        = cA;
        out[LSTM_B * LSTM_H + b * LSTM_H + 128 + jA]  = cB;
    }
}

extern "C" void kernel_launch(void* const* d_in, const int* in_sizes, int n_in,
                              void* d_out, int out_size, void* d_ws, size_t ws_size,
                              hipStream_t stream) {
    const float* xs   = (const float*)d_in[0];  // [64,4096,256]
    const float* W_ih = (const float*)d_in[1];  // [1024,256]
    const float* W_hh = (const float*)d_in[2];  // [1024,256]
    const float* b    = (const float*)d_in[3];  // [1024]
    float* out = (float*)d_out;
    uint32_t* Wp = (uint32_t*)d_ws;             // 1 MiB packed f16 weights

    prep_weights<<<1024, 256, 0, stream>>>(W_ih, W_hh, Wp);
    lstm_r8<<<LSTM_B, 512, 0, stream>>>(xs, b, (const uint4*)Wp, out);
}